// Round 4
// baseline (99.347 us; speedup 1.0000x reference)
//
#include <hip/hip_runtime.h>
#include <stdint.h>

// HamiltonianFlow: x [256, 8, 32, 2] (q,p); H = 0.5*sum(p^2) + MLP(q).
// dq/dt = p, dp/dt = -W u(z), z = W^T q + b1, u = (1-tanh^2(z)).*W2.
// z-space iteration with M = W^T W (R15-R23 verified).
//
// R28 = R27 (16 waves x 1 tile, 4-step exchange) + PRODUCE/CONSUME
// SOFTWARE PIPELINE. R27's counters showed the wall is phase-burst
// serialization: all 16 barrier-lockstepped waves hit LDS, then MFMA,
// then the u-eval VALU burst in the same phase -> no cross-wave hiding.
// Fix: compute u(e+1) DURING exchange e's MFMA. Loop body is now
//   barrier -> [A-reads + MFMA(e)] || [S-accum(e); predict state(e);
//   eval u(e+1); write buf[(e+1)&1]] -> wait MFMA; bfly; exact update.
// u(e+1) needs only state(e-1) + SB/SV(e-1) + Y-lags(e-1):
//   Pf  = P - dt6*SBp                    (pred P(e),  SBp ~ SB(e) proxy)
//   z2f = 2z + 8dt*P - 2dtdt6*SVp        (pred 2z(e), SVp ~ SV(e) proxy)
//   then the R25/R27 per-quad stage formulas on (z2f, Pf) with lag-2
//   SBp/SVp and lag-2 own-step Y1L/Y2L. All proxy errors enter scaled by
//   dtdt6 ~ 1.7e-5 (or 4e-4 on P * j*dt ~ 0.03) -> ~1e-5-class stage-z
//   error, ~2 orders below the f16 u-rounding floor. 4-step state update
//   stays EXACT: z += 4dt*P - dtdt6*SV(e); P -= dt6*SB(e).
// Race-safety (R24 argument, unchanged): writes to buf[(e+1)&1] happen
// after barrier(e), which all waves reach only after completing their
// exchange-(e-1) reads of that same buffer. ONE barrier per 4 steps.
// e=24 computes/writes a dead u(25) into buf1 (never read) - harmless.
// ubuf rows 4*step+stage; XOR col-swizzle (c ^= ((row>>2)&3)<<3) kills
// 4-row ds_read_b128 aliasing. mscr 16x320 f32 UNIONs ubuf (barriered).
// FULL unroll on every reg-array access (R4: dynamic index => scratch).
// Numerics: f16 storage (W, M, u, S), fp32 MFMA accum + fp32 z/P state.

typedef _Float16 v8h __attribute__((ext_vector_type(8)));
typedef float v4f __attribute__((ext_vector_type(4)));

#define NSTEPS 100
#define NEX 25    // 4 RK4 steps per exchange
#define WS 264    // wldsT row stride (f16): row = one W-COLUMN, 16B-aligned
#define US 272    // ubuf row stride, f16 (544 B == 32 mod 128)

// D(+=C) in VGPRs, A (packed-vector frag) in VGPRs, B (M-frag) from AGPRs.
#define MFMA_AV(C, A, B) \
    asm("v_mfma_f32_16x16x32_f16 %0, %1, %2, %0" : "+v"(C) : "v"(A), "a"(B))

// 4-group butterfly sum over lanes {l, l^16, l^32, l^48}, pure VALU.
__device__ __forceinline__ float bfly4(float x) {
    float a = x, b = x;
    asm("v_permlane16_swap_b32 %0, %1" : "+v"(a), "+v"(b));
    float s = a + b;
    float c = s, d = s;
    asm("v_permlane32_swap_b32 %0, %1" : "+v"(c), "+v"(d));
    return c + d;
}

// u/(4*w2) eval on pre-doubled arg zz = 2*z:  r = rcp(e^zz + 1);
// u = 4*w2*(r - r^2)  ==  (1 - tanh^2(z)) * w2  exactly in algebra.
__device__ __forceinline__ float ueval2(float zz, float w4) {
    float e_ = __expf(zz);
    float r_ = __builtin_amdgcn_rcpf(e_ + 1.f);   // vs IEEE div: ~1e-7 rel
    return w4 * __builtin_fmaf(-r_, r_, r_);
}

__global__ __launch_bounds__(1024, 4)
void ham_kernel(const float* __restrict__ x0, const float* __restrict__ W1,
                const float* __restrict__ b1, const float* __restrict__ W2,
                float* __restrict__ out)
{
    __shared__ __align__(16)  _Float16 wldsT[256 * WS];  // 135168 B: W^T (f16)
    __shared__ __align__(128) char     upool[20480];     // mscr UNION ubuf
    float*    mscr = (float*)upool;                      // setup only
    _Float16* ubuf = (_Float16*)upool;                   // 2 x 16 rows x US

    const int t = threadIdx.x;
    const int w = t >> 6;          // wave 0..15: owns tile w (16 comps)
    const int l = t & 63;
    const int quad = l >> 4;       // step-within-exchange owned by this lane
    const int s = l & 15;          // owned column / A-row
    const int c0 = 16 * w + s;     // owned component
    const int blk = blockIdx.x;
    const int sel = (s & 3) * US;  // prologue/epilogue A-row select (rows 0-3)

    // ---- stage W^T -> LDS f16: wldsT[c][r] = W[r][c] ----
    {
        const int c = t & 255;
        const int rbase = (t >> 8) * 64;   // 4 quarters x 64 rows
        #pragma unroll 1
        for (int r0 = 0; r0 < 64; r0 += 8) {
            v8h h;
            #pragma unroll
            for (int j = 0; j < 8; ++j)
                h[j] = (_Float16)W1[(rbase + r0 + j) * 256 + c];
            *(v8h*)(wldsT + c * WS + rbase + r0) = h;   // b128, one-time
        }
    }
    __syncthreads();

    // ---- wF: own-column W^T frag (B-op), contiguous b128 from wldsT ----
    v8h wF0[8];
    #pragma unroll
    for (int kk = 0; kk < 8; ++kk)
        wF0[kk] = *(const v8h*)(wldsT + c0 * WS + 32 * kk + 8 * quad);

    // ---- build M = W^T W column-block frags wM0 (B-op: M[k][c0]) ----
    v8h wM0[8];
    float* scr0 = mscr + w * 320;
    #pragma unroll
    for (int kb = 0; kb < 16; ++kb) {
        v8h aM[8];   // A[m=s][k=8quad+j] = wldsT[(16kb+s)*WS + 32kk+8quad+j]
        #pragma unroll
        for (int kk = 0; kk < 8; ++kk)
            aM[kk] = *(const v8h*)(wldsT + (16 * kb + s) * WS
                                          + 32 * kk + 8 * quad);
        v4f D0 = {0.f,0.f,0.f,0.f};
        #pragma unroll
        for (int kk = 0; kk < 8; ++kk)
            D0 = __builtin_amdgcn_mfma_f32_16x16x32_f16(aM[kk], wF0[kk], D0, 0, 0, 0);
        *(v4f*)(scr0 + s * 20 + 4 * quad) = D0;
        asm volatile("s_waitcnt lgkmcnt(0)" ::: "memory");  // in-wave x-lane
        if ((quad >> 1) == (kb & 1)) {
            #pragma unroll
            for (int j = 0; j < 8; ++j)
                wM0[kb >> 1][j] = (_Float16)scr0[s * 20 + 8 * (quad & 1) + j];
        }
        asm volatile("s_waitcnt lgkmcnt(0)" ::: "memory");
    }
    __syncthreads();   // mscr reads (all waves) done before ubuf reuse

    const float b1r0 = b1[c0];
    const float w4 = 4.f * W2[c0];
    float2 qp0 = ((const float2*)(x0 + (size_t)blk * 512))[c0];
    const float q0o0 = qp0.x, p0o0 = qp0.y;

    // ---- prologue: buf0 rows {q0, p0, 0, 0} -> z1 (C[0]), P (C[1]) ----
    if (quad == 0) {
        ubuf[c0] = (_Float16)q0o0;
        ubuf[US + c0] = (_Float16)p0o0;
        ubuf[2 * US + c0] = (_Float16)0.f;
        ubuf[3 * US + c0] = (_Float16)0.f;
    }
    __syncthreads();
    float z1, P;
    {
        const _Float16* ab = ubuf + sel + 8 * quad;
        v4f C0a = {0.f,0.f,0.f,0.f}, C0b = {0.f,0.f,0.f,0.f};
        #pragma unroll
        for (int kk = 0; kk < 8; kk += 2) {
            v8h a0 = *(const v8h*)(ab + 32 * kk);
            v8h a1 = *(const v8h*)(ab + 32 * (kk + 1));
            C0a = __builtin_amdgcn_mfma_f32_16x16x32_f16(a0, wF0[kk], C0a, 0, 0, 0);
            C0b = __builtin_amdgcn_mfma_f32_16x16x32_f16(a1, wF0[kk + 1], C0b, 0, 0, 0);
        }
        v4f C0s = C0a + C0b;
        z1 = C0s[0] + b1r0;  P = C0s[1];
    }
    __syncthreads();   // prologue reads done before u(0) overwrites buf0

    const float dt = 0.01f, hdt = 0.005f, dt6 = 0.01f / 6.f;
    const float dtdt6 = dt * dt6, hdt2 = hdt * hdt, dthdt = dt * hdt;
    const float fourdt = 4.f * dt;
    const float K8dt = 8.f * dt;
    const float K2dtdt6n = -2.f * dtdt6;
    // per-quad (step j = quad) prediction coefs in {SBp, SVp} form:
    //   Pp = Pf - (j/4)dt6*SBp
    //   zp2 = z2f + 2j*dt*Pf + [j(4-j)dtdt6/4]*SBp - [j*dtdt6/2]*SVp
    const float qf  = (float)quad;
    const float cPn   = -(qf * 0.25f * dt6);
    const float K2cz1 = 2.f * qf * dt;
    const float K2B   = qf * (4.f - qf) * dtdt6 * 0.25f;
    const float K2Vn  = -(qf * dtdt6 * 0.5f);
    const float K2hdt = 2.f * hdt;
    const float K2hdt2n = -2.f * hdt2;
    const float K2dt  = 2.f * dt;
    const float K2dthdtn = -2.f * dthdt;
    const float wB  = 3.f - qf;          // SWB weight (3-j)

    // ubuf addressing: write rows 4q+i at swizzled col c ^ (q<<3);
    // read row s at k-chunk 8*(quad ^ ((s>>2)&3))  [XOR involution]
    const int c0w = c0 ^ (quad << 3);
    _Float16* wbase0 = ubuf + 4 * quad * US + c0w;
    const int sx = (s >> 2) & 3;
    const _Float16* rb = ubuf + s * US + 8 * (quad ^ sx);

    // lag state (SB/SV/Y from the most recent completed exchange)
    float SBp = 0.f, SVp = 0.f;
    float Y1L = 0.f, Y2L = 0.f;
    float S1p = 0.f, S23p = 0.f;
    float cn = 99.f - qf;

    // ---- pre-loop: compute u(0) from raw state (zero lags), write buf0 ----
    float ua, ub, uc, ud;
    {
        float zp2 = __builtin_fmaf(K2cz1, P, z1 + z1);
        float zb2 = __builtin_fmaf(K2hdt, P, zp2);
        float zc2 = zb2;                               // Y1L = 0
        float zd2 = __builtin_fmaf(K2dt, P, zp2);      // Y2L = 0
        ua = ueval2(zp2, w4);
        ub = ueval2(zb2, w4);
        uc = ueval2(zc2, w4);
        ud = ueval2(zd2, w4);
        wbase0[0]      = (_Float16)ua;
        wbase0[US]     = (_Float16)ub;
        wbase0[2 * US] = (_Float16)uc;
        wbase0[3 * US] = (_Float16)ud;
    }

    #pragma unroll 1
    for (int e = 0; e < NEX; ++e) {
        const int bo = (e & 1) * (16 * US);   // double-buffer offset

        __syncthreads();   // all waves' u(e) writes visible (ONLY barrier)

        // ---- MFMA block reading buf[e&1]: issue reads + chains first ----
        v4f C0a = {0.f,0.f,0.f,0.f}, C0b = {0.f,0.f,0.f,0.f};
        {
            const _Float16* ab = rb + bo;
            #pragma unroll
            for (int kk = 0; kk < 8; kk += 2) {
                v8h a0 = *(const v8h*)(ab + 32 * kk);
                v8h a1 = *(const v8h*)(ab + 32 * (kk + 1));
                MFMA_AV(C0a, a0, wM0[kk]);
                MFMA_AV(C0b, a1, wM0[kk + 1]);
            }
        }

        // ---- overlap: S-accum(e) with the in-reg u(e) ----
        {
            float tv = ub + uc;
            float sp = __builtin_fmaf(2.f, tv, ua + ud);
            float sq = ua + tv;
            S1p += sp;
            S23p = __builtin_fmaf(cn, sp, S23p) + sq;
            cn -= 4.f;
        }

        // ---- overlap: predict state(e), eval u(e+1)  [no MFMA dep] ----
        {
            float Pf  = __builtin_fmaf(-dt6, SBp, P);        // pred P(e)
            float z2f = __builtin_fmaf(K8dt, P, z1 + z1);    // pred 2z(e)
            z2f = __builtin_fmaf(K2dtdt6n, SVp, z2f);
            float Pp  = __builtin_fmaf(cPn, SBp, Pf);
            float zp2 = __builtin_fmaf(K2cz1, Pf, z2f);
            zp2 = __builtin_fmaf(K2B, SBp, zp2);
            zp2 = __builtin_fmaf(K2Vn, SVp, zp2);
            float zb2 = __builtin_fmaf(K2hdt, Pp, zp2);
            float zc2 = __builtin_fmaf(K2hdt2n, Y1L, zb2);
            float zd2 = __builtin_fmaf(K2dt, Pp, zp2);
            zd2 = __builtin_fmaf(K2dthdtn, Y2L, zd2);
            ua = ueval2(zp2, w4);
            ub = ueval2(zb2, w4);
            uc = ueval2(zc2, w4);
            ud = ueval2(zd2, w4);
        }

        // ---- overlap: write u(e+1) -> buf[(e+1)&1] (after barrier(e):
        //      all waves finished exchange-(e-1) reads of that buffer) ----
        {
            _Float16* wp0 = wbase0 + (bo ^ (16 * US));
            wp0[0]      = (_Float16)ua;
            wp0[US]     = (_Float16)ub;
            wp0[2 * US] = (_Float16)uc;
            wp0[3 * US] = (_Float16)ud;
        }

        // ---- consume MFMA: bfly sums; EXACT 4-step state advance ----
        v4f C0s = C0a + C0b;
        float Y1 = C0s[0], Y2 = C0s[1], Y3 = C0s[2], Y4 = C0s[3];
        float tA = Y2 + Y3;
        float A  = Y1 + tA;                    // Y1+Y2+Y3
        float B  = A + tA + Y4;                // Y1+2Y2+2Y3+Y4
        float V  = __builtin_fmaf(wB, B, A);   // (3-j)*B + A
        float SB = bfly4(B);
        float SV = bfly4(V);                   // = SWB + SA (exact)

        z1 = __builtin_fmaf(fourdt, P, z1);    // z += 4dt*P (old P)
        z1 = __builtin_fmaf(-dtdt6, SV, z1);   //    - dt*dt6*SWB - dtdt6*SA
        P  = __builtin_fmaf(-dt6, SB, P);      // P -= dt6*SB

        SBp = SB;  SVp = SV;  Y1L = Y1;  Y2L = Y2;   // refresh lags
    }
    // note: iter e=24 computed/wrote a dead u(25) into buf1 - never read.

    // ---- epilogue: reduce S over the 4 quads; buf0 rows {S1, S23, 0, 0} ----
    const float S1f  = bfly4(S1p);
    const float S23f = bfly4(S23p);
    __syncthreads();   // last exchange's reads (buf0, e=24) done
    if (quad == 0) {
        ubuf[c0] = (_Float16)S1f;
        ubuf[US + c0] = (_Float16)S23f;
        ubuf[2 * US + c0] = (_Float16)0.f;
        ubuf[3 * US + c0] = (_Float16)0.f;
    }
    __syncthreads();
    // wBt[kk][j] = W[c0][32kk+8quad+j] = wldsT[(32kk+8quad+j)*WS + c0]
    v8h wBt0[8];
    #pragma unroll
    for (int kk = 0; kk < 8; ++kk)
        #pragma unroll
        for (int j = 0; j < 8; ++j)
            wBt0[kk][j] = wldsT[(32 * kk + 8 * quad + j) * WS + c0];
    float D10, D20;
    {
        const _Float16* ab = ubuf + sel + 8 * quad;
        v4f C0a = {0.f,0.f,0.f,0.f}, C0b = {0.f,0.f,0.f,0.f};
        #pragma unroll
        for (int kk = 0; kk < 8; kk += 2) {
            v8h a0 = *(const v8h*)(ab + 32 * kk);
            v8h a1 = *(const v8h*)(ab + 32 * (kk + 1));
            C0a = __builtin_amdgcn_mfma_f32_16x16x32_f16(a0, wBt0[kk], C0a, 0, 0, 0);
            C0b = __builtin_amdgcn_mfma_f32_16x16x32_f16(a1, wBt0[kk + 1], C0b, 0, 0, 0);
        }
        v4f C0s = C0a + C0b;
        D10 = C0s[0];  D20 = C0s[1];
    }
    const float dt6e = 0.01f / 6.f, dtdt6e = 0.01f * dt6e;
    float pT0 = p0o0 - dt6e * D10;
    float qT0 = q0o0 + 0.01f * (float)NSTEPS * p0o0 - dtdt6e * D20;

    if (quad == 0)
        ((float2*)(out + (size_t)blk * 512))[c0] = make_float2(qT0, pT0);
}

extern "C" void kernel_launch(void* const* d_in, const int* in_sizes, int n_in,
                              void* d_out, int out_size, void* d_ws, size_t ws_size,
                              hipStream_t stream) {
    const float* x0 = (const float*)d_in[0];
    const float* W1 = (const float*)d_in[1];
    const float* b1 = (const float*)d_in[2];
    const float* W2 = (const float*)d_in[3];
    // d_in[4] = b2: constant offset, no effect on the gradient/dynamics.
    float* out = (float*)d_out;
    hipLaunchKernelGGL(ham_kernel, dim3(256), dim3(1024), 0, stream,
                       x0, W1, b1, W2, out);
}